// Round 8
// baseline (90.904 us; speedup 1.0000x reference)
//
#include <hip/hip_runtime.h>

#define N_EMB   8192
#define D_EMB   128
#define NSTEPS  201
#define NB      64                   // 8192 / 128 tiles per dim
#define TBLOCKS (NB*(NB+1)/2)        // 2080 upper-tri 128x128 tiles incl. diagonal
#define NCOPY   16                   // replicated global histogram copies
#define NHIST   16                   // per-quarter-wave LDS copies (per sign table)

typedef __attribute__((ext_vector_type(8))) short bf16x8;
typedef __attribute__((ext_vector_type(4))) float f32x4;

// packed per-bin accumulator: (count << 21) | fq, fq = round(frac*1024)
#define CNT_SHIFT  21
#define FRAC_MASK  ((1u << CNT_SHIFT) - 1u)
#define NZERO      (NCOPY * 2 * NSTEPS)      // floats to zero in ghist

__device__ __forceinline__ unsigned short f2bf(float f) {
  unsigned int u = __builtin_bit_cast(unsigned int, f);
  u = (u + 0x7fffu + ((u >> 16) & 1u)) >> 16;   // RNE fp32 -> bf16
  return (unsigned short)u;
}

// ---- tile id -> (bi, bj), bi <= bj ----
__device__ __forceinline__ void tile_coords(int t, int& bi, int& bj) {
  int rem = TBLOCKS - 1 - t;
  int r   = (int)((sqrtf(8.0f*(float)rem + 1.0f) - 1.0f) * 0.5f);
  while ((r+1)*(r+2)/2 <= rem) ++r;
  while (r*(r+1)/2 > rem) --r;
  bi = NB - 1 - r;
  bj = NB - 1 - (rem - r*(r+1)/2);
}

// ---- pre-pass: fp32 -> bf16 fragment-tiled; zeroes ghist + done flag ----
__global__ __launch_bounds__(256) void convert_kernel(
    const float* __restrict__ x1, const float* __restrict__ x2,
    unsigned short* __restrict__ x1b, unsigned short* __restrict__ x2b,
    float* __restrict__ ghist, unsigned int* __restrict__ gdone)
{
  int t = blockIdx.x * 256 + threadIdx.x;
  if (t < NZERO) ghist[t] = 0.0f;
  else if (t == NZERO) gdone[0] = 0u;
  const float*    src = (t < 131072) ? x1  : x2;
  unsigned short* dst = (t < 131072) ? x1b : x2b;
  int tt  = t & 131071;
  int r   = tt >> 4;
  int c16 = tt & 15;
  const float4* g = reinterpret_cast<const float4*>(src + ((size_t)r << 7) + c16*8);
  float4 v0 = g[0], v1 = g[1];
  int R = r >> 4, fr = r & 15, K = c16 >> 2, kg = c16 & 3;
  size_t chunk = ((size_t)(R*4 + K) << 6) + (size_t)(kg*16 + fr);
  uint4 p;
  p.x = f2bf(v0.x) | ((unsigned int)f2bf(v0.y) << 16);
  p.y = f2bf(v0.z) | ((unsigned int)f2bf(v0.w) << 16);
  p.z = f2bf(v1.x) | ((unsigned int)f2bf(v1.y) << 16);
  p.w = f2bf(v1.z) | ((unsigned int)f2bf(v1.w) << 16);
  *reinterpret_cast<uint4*>(dst + chunk*8) = p;
}

// ============ main: 128x128 tile per block, both histograms, fused finalize ============
__global__ __launch_bounds__(256, 4) void main_kernel(
    const unsigned short* __restrict__ x1b, const unsigned short* __restrict__ x2b,
    const float* __restrict__ t1g, const float* __restrict__ t2g,
    float* __restrict__ ghist, unsigned int* __restrict__ gdone,
    float* __restrict__ out)
{
  __shared__ unsigned int whist[2][NHIST][NSTEPS];   // [pos/neg][copy][bin]
  __shared__ float hfin[2][NSTEPS];                  // finalize scratch
  __shared__ int lastFlag;

  const int tid = threadIdx.x;
  for (int b = tid; b < 2*NHIST*NSTEPS; b += 256) ((unsigned int*)whist)[b] = 0u;

  const int lane = tid & 63;
  const int w    = tid >> 6;
  const int wr   = w >> 1, wc = w & 1;
  const int fr   = lane & 15;
  const int kg   = lane >> 4;
  const int rbase = kg * 4;
  unsigned int* whP = &whist[0][(w << 2) | kg][0];
  const int NEGOFF = NHIST * NSTEPS;

  int bi, bj; tile_coords((int)blockIdx.x, bi, bj);
  const int gi0 = bi*128, gj0 = bj*128;
  const bool full = (bi != bj);

  const int Ra = (gi0 >> 4) + wr*4;   // A row-block base (16-row units)
  const int Rb = (gj0 >> 4) + wc*4;   // B row-block base

  __syncthreads();                    // whist zeroing visible

  // ---- MFMA: each wave a 64x64 quadrant = 4x4 of 16x16 tiles, K=128 ----
  f32x4 acc[4][4];
#pragma unroll
  for (int m = 0; m < 4; ++m)
#pragma unroll
    for (int n = 0; n < 4; ++n) acc[m][n] = f32x4{0.f,0.f,0.f,0.f};

#pragma unroll
  for (int ks = 0; ks < 4; ++ks) {
    bf16x8 af[4], bf[4];
#pragma unroll
    for (int q = 0; q < 4; ++q) {
      af[q] = *reinterpret_cast<const bf16x8*>(x1b + ((((size_t)(Ra+q)*4 + ks)*64 + lane) << 3));
      bf[q] = *reinterpret_cast<const bf16x8*>(x2b + ((((size_t)(Rb+q)*4 + ks)*64 + lane) << 3));
    }
#pragma unroll
    for (int m = 0; m < 4; ++m)
#pragma unroll
      for (int n = 0; n < 4; ++n)
        acc[m][n] = __builtin_amdgcn_mfma_f32_16x16x32_bf16(af[m], bf[n], acc[m][n], 0, 0, 0);
  }

  // ---- targets from global (L1/L2-resident broadcasts) ----
  float T2v[4][4], T1v[4];
#pragma unroll
  for (int m = 0; m < 4; ++m)
#pragma unroll
    for (int rr = 0; rr < 4; ++rr) T2v[m][rr] = t2g[gi0 + wr*64 + m*16 + rbase + rr];
#pragma unroll
  for (int n = 0; n < 4; ++n) T1v[n] = t1g[gj0 + wc*64 + n*16 + fr];

  // ---- deposit: one packed u32 LDS atomic per pair ----
  // C/D layout (m89/m91): col = lane&15, row = (lane>>4)*4 + reg
#pragma unroll
  for (int m = 0; m < 4; ++m) {
#pragma unroll
    for (int n = 0; n < 4; ++n) {
      const int lj = wc*64 + n*16 + fr;
      const float t1v = T1v[n];
#pragma unroll
      for (int rr = 0; rr < 4; ++rr) {
        const int li = wr*64 + m*16 + rbase + rr;
        bool pos = (T2v[m][rr] * t1v > 0.0f);
        float uu = fmaf(acc[m][n][rr], 102400.0f, 102400.5f);
        int   iu = (int)uu;
        int  idx = iu >> 10;
        idx = idx < 0 ? 0 : (idx > NSTEPS-1 ? NSTEPS-1 : idx);
        unsigned int pk = (1u << CNT_SHIFT) | (unsigned int)(iu & 1023);
        unsigned int* dst = whP + (pos ? 0 : NEGOFF) + idx;
        if (full || (lj > li)) atomicAdd(dst, pk);
      }
    }
  }
  __syncthreads();

  // ---- unpack + flush:  h[b] = cnt[b] - fr[b]/1024 + fr[b-1]/1024 ; h[200] = cnt[200] + fr[199]/1024
  float* gh = ghist + (size_t)(blockIdx.x & (NCOPY-1)) * (2*NSTEPS);
  if (tid < NSTEPS) {
    const int b = tid;
    const float inv = 1.0f / 1024.0f;
#pragma unroll
    for (int sg = 0; sg < 2; ++sg) {
      unsigned int cp = 0; float fp = 0.f, fpm1 = 0.f;
#pragma unroll
      for (int ww = 0; ww < NHIST; ++ww) {
        unsigned int vp = whist[sg][ww][b];
        cp += vp >> CNT_SHIFT;  fp += (float)(vp & FRAC_MASK);
        if (b > 0) fpm1 += (float)(whist[sg][ww][b-1] & FRAC_MASK);
      }
      float hv = (b == NSTEPS-1) ? ((float)cp + fpm1 * inv)
                                 : ((float)cp - fp * inv + fpm1 * inv);
      if (hv != 0.0f) atomicAdd(&gh[sg*NSTEPS + b], hv);
    }
  }

  // ---- last block finalizes (ticket; result independent of which block) ----
  if (tid == 0) {
    __threadfence();
    unsigned int prev = atomicAdd(gdone, 1u);
    lastFlag = (prev == (unsigned int)(TBLOCKS - 1));
  }
  __syncthreads();
  if (lastFlag) {
    __threadfence();
    if (tid < NSTEPS) {
      float sp = 0.f, sn = 0.f;
      const volatile float* gv = ghist;
#pragma unroll
      for (int c = 0; c < NCOPY; ++c) {
        sp += gv[(size_t)c*(2*NSTEPS) + tid];
        sn += gv[(size_t)c*(2*NSTEPS) + NSTEPS + tid];
      }
      hfin[0][tid] = sp; hfin[1][tid] = sn;
    }
    __syncthreads();
    if (tid == 0) {
      const float TOT = 33550336.0f;            // N*(N-1)/2
      float np = 0.f;
      for (int b = 0; b < NSTEPS; ++b) np += hfin[0][b];
      float nn = TOT - np;
      float ip  = 1.0f / fmaxf(np, 1.0f);
      float in_ = 1.0f / fmaxf(nn, 1.0f);
      float cdf = 0.f, loss = 0.f;
      for (int b = 0; b < NSTEPS; ++b) {
        cdf  += hfin[0][b] * ip;
        loss += hfin[1][b] * in_ * cdf;
      }
      out[0] = loss;
    }
  }
}

extern "C" void kernel_launch(void* const* d_in, const int* in_sizes, int n_in,
                              void* d_out, int out_size, void* d_ws, size_t ws_size,
                              hipStream_t stream) {
  const float* x1 = (const float*)d_in[0];
  const float* x2 = (const float*)d_in[1];
  const float* t1 = (const float*)d_in[2];
  const float* t2 = (const float*)d_in[3];
  float* out = (float*)d_out;

  const size_t BF_BYTES = (size_t)N_EMB * D_EMB * sizeof(unsigned short);  // 2 MB each
  char* p = (char*)d_ws;
  unsigned short* x1b   = (unsigned short*)p;   p += BF_BYTES;
  unsigned short* x2b   = (unsigned short*)p;   p += BF_BYTES;
  float*          ghist = (float*)p;            p += (size_t)NZERO*sizeof(float);
  unsigned int*   gdone = (unsigned int*)p;

  convert_kernel<<<(2*N_EMB*D_EMB/8 + 255)/256, 256, 0, stream>>>(x1, x2, x1b, x2b, ghist, gdone);
  main_kernel<<<TBLOCKS, 256, 0, stream>>>(x1b, x2b, t1, t2, ghist, gdone, out);
}